// Round 1
// 178.876 us; speedup vs baseline: 1.0430x; 1.0430x over previous
//
#include <hip/hip_runtime.h>
#include <hip/hip_bf16.h>

// Problem constants
#define BB 2
#define SS 2048
#define HH 1024
#define NH 16
#define DD 64
#define H3 3072
#define MM (BB*SS)   // 4096 rows

typedef unsigned short u16;
typedef unsigned int u32;
typedef __attribute__((ext_vector_type(8))) short bf16x8;
typedef __attribute__((ext_vector_type(4))) float f32x4;

__device__ __forceinline__ u16 f2bf(float f) {
    union { float f; u32 u; } v; v.f = f;
    u32 u = v.u;
    u += 0x7fffu + ((u >> 16) & 1u);   // RNE
    return (u16)(u >> 16);
}
__device__ __forceinline__ float bf2f(u16 h) {
    union { u32 u; float f; } v; v.u = ((u32)h) << 16;
    return v.f;
}
__device__ __forceinline__ u32 pack2bf(float a, float b) {
    __hip_bfloat162 h = __float22bfloat162_rn(float2{a, b});
    u32 u; __builtin_memcpy(&u, &h, 4);
    return u;
}
// async global->LDS, 16B/lane; LDS dest = wave-uniform base + lane*16B.
__device__ __forceinline__ void gl_lds16(const void* g, void* l) {
    __builtin_amdgcn_global_load_lds(
        (const __attribute__((address_space(1))) u32*)g,
        (__attribute__((address_space(3))) u32*)l, 16, 0, 0);
}

// ---------------------------------------------------------------------------
// fp32 -> bf16 bulk convert, three buffers per launch
// ---------------------------------------------------------------------------
__global__ void cvt3bf(const float4* __restrict__ s0, uint2* __restrict__ d0, int n0,
                       const float4* __restrict__ s1, uint2* __restrict__ d1, int n1,
                       const float4* __restrict__ s2, uint2* __restrict__ d2, int n2) {
    int i = blockIdx.x * blockDim.x + threadIdx.x;
    const int tot = n0 + n1 + n2;
    for (; i < tot; i += gridDim.x * blockDim.x) {
        const float4* s; uint2* d; int j;
        if (i < n0)            { s = s0; d = d0; j = i; }
        else if (i < n0 + n1)  { s = s1; d = d1; j = i - n0; }
        else                   { s = s2; d = d2; j = i - n0 - n1; }
        float4 v = s[j];
        uint2 o; o.x = pack2bf(v.x, v.y); o.y = pack2bf(v.z, v.w);
        d[j] = o;
    }
}

// ---------------------------------------------------------------------------
// GEMM: C[M,N] = A[M,K] @ B[N,K]^T + bias.  BM=128, BK=32, BN template.
// A, B bf16, both staged via global_load_lds width-16 (m97 structure).
// MODE 1: fp32 out.  MODE 2: QKV epilogue -> Q (scaled 1/8), K, Vt (V^T).
// ---------------------------------------------------------------------------
template<int BN, int MODE>
__global__ __launch_bounds__(256, 2)
void gemm_k2(const u16* __restrict__ A, const u16* __restrict__ Bbf,
             const u16* __restrict__ biasbf, void* __restrict__ Cptr,
             u16* __restrict__ Qo, u16* __restrict__ Ko, u16* __restrict__ Vto,
             int M, int Nn, int K)
{
    constexpr int NFR = BN / 32;
    __shared__ __align__(16) u16 Alds[128 * 32];
    __shared__ __align__(16) u16 Blds[BN * 32];
    const int tid = threadIdx.x;
    const int w = tid >> 6, lane = tid & 63, quad = lane >> 4, l16 = lane & 15;
    const int m0 = blockIdx.x * 128, n0 = blockIdx.y * BN;
    const int wm = w >> 1, wn = w & 1;
    const int rA4 = lane >> 2, c8b = (lane & 3) * 8;   // gl_lds16: 4 lanes/row

    f32x4 acc[4][NFR] = {};

    for (int k0 = 0; k0 < K; k0 += 32) {
        __syncthreads();
        // A: wave w stages rows [w*32, w*32+32): 2 calls x 16 rows
#pragma unroll
        for (int q = 0; q < 2; ++q) {
            int row0 = w * 32 + q * 16;
            gl_lds16(&A[(size_t)(m0 + row0 + rA4) * K + k0 + c8b], &Alds[row0 * 32]);
        }
        // B: wave w stages rows [w*(BN/4), ...): BN/64 calls x 16 rows
#pragma unroll
        for (int q = 0; q < BN / 64; ++q) {
            int row0 = w * (BN / 4) + q * 16;
            gl_lds16(&Bbf[(size_t)(n0 + row0 + rA4) * K + k0 + c8b], &Blds[row0 * 32]);
        }
        __syncthreads();

        bf16x8 af[4], bfr[NFR];
#pragma unroll
        for (int mi = 0; mi < 4; ++mi)
            af[mi] = *(const bf16x8*)&Alds[(wm * 64 + mi * 16 + l16) * 32 + quad * 8];
#pragma unroll
        for (int ni = 0; ni < NFR; ++ni)
            bfr[ni] = *(const bf16x8*)&Blds[(wn * (BN / 2) + ni * 16 + l16) * 32 + quad * 8];
#pragma unroll
        for (int mi = 0; mi < 4; ++mi)
#pragma unroll
            for (int ni = 0; ni < NFR; ++ni)
                acc[mi][ni] = __builtin_amdgcn_mfma_f32_16x16x32_bf16(
                    af[mi], bfr[ni], acc[mi][ni], 0, 0, 0);
    }

    // epilogue: within 16x16 tile, row = quad*4+i, col = l16 (m89-verified)
#pragma unroll
    for (int mi = 0; mi < 4; ++mi) {
        int row_b = m0 + wm * 64 + mi * 16 + quad * 4;
#pragma unroll
        for (int ni = 0; ni < NFR; ++ni) {
            int col = n0 + wn * (BN / 2) + ni * 16 + l16;
            float bv = bf2f(biasbf[col]);
            if constexpr (MODE == 1) {
#pragma unroll
                for (int i = 0; i < 4; ++i)
                    ((float*)Cptr)[(size_t)(row_b + i) * Nn + col] = acc[mi][ni][i] + bv;
            } else {
                if (col < 1024) {            // Q, pre-scaled by 1/sqrt(D)
#pragma unroll
                    for (int i = 0; i < 4; ++i)
                        Qo[(size_t)(row_b + i) * 1024 + col] =
                            f2bf((acc[mi][ni][i] + bv) * 0.125f);
                } else if (col < 2048) {     // K
#pragma unroll
                    for (int i = 0; i < 4; ++i)
                        Ko[(size_t)(row_b + i) * 1024 + (col - 1024)] =
                            f2bf(acc[mi][ni][i] + bv);
                } else {                     // V -> Vt [b][h][d][s], pack 4 s
                    int d = col - 2048, hh = d >> 6, dd = d & 63;
                    int b = row_b >> 11, s = row_b & 2047;
                    u16 t0 = f2bf(acc[mi][ni][0] + bv), t1 = f2bf(acc[mi][ni][1] + bv);
                    u16 t2 = f2bf(acc[mi][ni][2] + bv), t3 = f2bf(acc[mi][ni][3] + bv);
                    uint2 pk; pk.x = (u32)t0 | ((u32)t1 << 16);
                    pk.y = (u32)t2 | ((u32)t3 << 16);
                    *(uint2*)&Vto[((size_t)((b * 16 + hh) * 64 + dd)) * 2048 + s] = pk;
                }
            }
        }
    }
}

// ---------------------------------------------------------------------------
// Causal flash attention v4.
// Swapped QK^T: S^T = mfma(K, Q) so each lane holds a full 16-value slice of
// ONE q row (q = l16).  K staging rows are bit-permuted (g=(m,q,a,i) ->
// R=(m,a,q,i)) so that S^T slot (ni,quad,i) lands at PV k-position
// 32*(ni>>1)+8*quad+4*(ni&1)+i.  Result: the P->A-fragment transpose is an
// IDENTITY in registers -- pf words are just the cvt_pk pairs.  No P LDS
// buffer, no scalar ds_writes (the 4.9M bank-conflict source), packed bf16
// converts, causal mask applied only on the diagonal tile, l-reduction =
// per-lane sum + 2 butterflies.  K/V double-buffered, 1 barrier per tile.
// ---------------------------------------------------------------------------
__global__ __launch_bounds__(256, 2)
void attn_v4(const u16* __restrict__ Q, const u16* __restrict__ Kb,
             const u16* __restrict__ Vt, u16* __restrict__ attn_out) {
    const int pr = blockIdx.x, h = blockIdx.y, b = blockIdx.z;
    const int tid = threadIdx.x;
    const int w = tid >> 6, lane = tid & 63, quad = lane >> 4, l16 = lane & 15;
    __shared__ __align__(16) u16 Klds[2][64 * 72];
    __shared__ __align__(16) u16 Vlds[2][64 * 72];
    const int r0 = tid >> 3, cc8 = (tid & 7) * 8;    // K/V staging map
    // K staging row permutation: global row g (bits m|q1 q0|a|i1 i0) -> LDS
    // row R (bits m|a|q1 q0|i1 i0).  Bijective bit-permute; +32 passes m.
    const int Rp = ((r0 & 4) << 2) | ((r0 & 24) >> 1) | (r0 & 3);

    for (int half = 0; half < 2; ++half) {
        const int qt = half ? pr : (31 - pr);        // uniform 33 iters/block
        const int q0 = qt * 64;
        const int T = qt + 1;

        const u16* Qb = Q  + (size_t)(b * SS + q0) * 1024 + h * 64;
        const u16* Kg = Kb + (size_t)(b * SS) * 1024 + h * 64;
        const u16* Vg = Vt + (size_t)((b * 16 + h) * 64) * 2048;

        bf16x8 qf0 = *(const bf16x8*)&Qb[(size_t)(w * 16 + l16) * 1024 + quad * 8];
        bf16x8 qf1 = *(const bf16x8*)&Qb[(size_t)(w * 16 + l16) * 1024 + 32 + quad * 8];

        f32x4 oacc[4] = {};
        float lp = 0.f;

        // preamble: tile 0 -> regs -> buf 0 (barrier first: prior half's
        // last reads of buf0 must be done before overwrite)
        uint4 kr0 = *(const uint4*)&Kg[(size_t)r0 * 1024 + cc8];
        uint4 kr1 = *(const uint4*)&Kg[(size_t)(r0 + 32) * 1024 + cc8];
        uint4 vr0 = *(const uint4*)&Vg[(size_t)r0 * 2048 + cc8];
        uint4 vr1 = *(const uint4*)&Vg[(size_t)(r0 + 32) * 2048 + cc8];
        __syncthreads();
        *(uint4*)&Klds[0][Rp * 72 + cc8]        = kr0;
        *(uint4*)&Klds[0][(Rp + 32) * 72 + cc8] = kr1;
        *(uint4*)&Vlds[0][r0 * 72 + cc8]        = vr0;
        *(uint4*)&Vlds[0][(r0 + 32) * 72 + cc8] = vr1;

        for (int t = 0; t < T; ++t) {
            const int cur = t & 1;
            __syncthreads();   // staging of tile t visible; reads of buf cur^1 done
            if (t + 1 < T) {   // prefetch tile t+1 into regs (overlaps compute)
                const int nv = (t + 1) * 64;
                kr0 = *(const uint4*)&Kg[(size_t)(nv + r0) * 1024 + cc8];
                kr1 = *(const uint4*)&Kg[(size_t)(nv + r0 + 32) * 1024 + cc8];
                vr0 = *(const uint4*)&Vg[(size_t)r0 * 2048 + nv + cc8];
                vr1 = *(const uint4*)&Vg[(size_t)(r0 + 32) * 2048 + nv + cc8];
            }
            // ---- S^T = K Q^T : 64 kv (rows, permuted) x 16 q (cols) ----
            f32x4 sacc[4] = {};
#pragma unroll
            for (int ni = 0; ni < 4; ++ni) {
                bf16x8 kf0 = *(const bf16x8*)&Klds[cur][(ni * 16 + l16) * 72 + quad * 8];
                bf16x8 kf1 = *(const bf16x8*)&Klds[cur][(ni * 16 + l16) * 72 + 32 + quad * 8];
                sacc[ni] = __builtin_amdgcn_mfma_f32_16x16x32_bf16(kf0, qf0, sacc[ni], 0, 0, 0);
                sacc[ni] = __builtin_amdgcn_mfma_f32_16x16x32_bf16(kf1, qf1, sacc[ni], 0, 0, 0);
            }
            // ---- P = exp(S): in-register, packed; mask only diagonal tile ----
            u32 pk[4][2];
            if (t + 1 < T) {                 // interior: kv < q0 <= q, no mask
#pragma unroll
                for (int ni = 0; ni < 4; ++ni) {
                    float p0 = __expf(sacc[ni][0]), p1 = __expf(sacc[ni][1]);
                    float p2 = __expf(sacc[ni][2]), p3 = __expf(sacc[ni][3]);
                    lp += (p0 + p1) + (p2 + p3);
                    pk[ni][0] = pack2bf(p0, p1);
                    pk[ni][1] = pack2bf(p2, p3);
                }
            } else {                         // diagonal: keep kv-pos <= w*16+l16
                const int thr = w * 16 + l16;
#pragma unroll
                for (int ni = 0; ni < 4; ++ni) {
                    const int pb = 32 * (ni >> 1) + 8 * quad + 4 * (ni & 1);
                    float pv[4];
#pragma unroll
                    for (int i = 0; i < 4; ++i) {
                        float e = __expf(sacc[ni][i]);
                        pv[i] = (pb + i <= thr) ? e : 0.f;
                    }
                    lp += (pv[0] + pv[1]) + (pv[2] + pv[3]);
                    pk[ni][0] = pack2bf(pv[0], pv[1]);
                    pk[ni][1] = pack2bf(pv[2], pv[3]);
                }
            }
            // P A-fragment = identity repack (thanks to K row permutation)
            union { u32 u[4]; bf16x8 v; } pf0, pf1;
            pf0.u[0] = pk[0][0]; pf0.u[1] = pk[0][1];
            pf0.u[2] = pk[1][0]; pf0.u[3] = pk[1][1];
            pf1.u[0] = pk[2][0]; pf1.u[1] = pk[2][1];
            pf1.u[2] = pk[3][0]; pf1.u[3] = pk[3][1];
            // ---- O += P V ----
#pragma unroll
            for (int ni = 0; ni < 4; ++ni) {
                bf16x8 vf0 = *(const bf16x8*)&Vlds[cur][(ni * 16 + l16) * 72 + quad * 8];
                bf16x8 vf1 = *(const bf16x8*)&Vlds[cur][(ni * 16 + l16) * 72 + 32 + quad * 8];
                oacc[ni] = __builtin_amdgcn_mfma_f32_16x16x32_bf16(pf0.v, vf0, oacc[ni], 0, 0, 0);
                oacc[ni] = __builtin_amdgcn_mfma_f32_16x16x32_bf16(pf1.v, vf1, oacc[ni], 0, 0, 0);
            }
            // ---- stage tile t+1 into the other buffer ----
            if (t + 1 < T) {
                const int nxt = cur ^ 1;
                *(uint4*)&Klds[nxt][Rp * 72 + cc8]        = kr0;
                *(uint4*)&Klds[nxt][(Rp + 32) * 72 + cc8] = kr1;
                *(uint4*)&Vlds[nxt][r0 * 72 + cc8]        = vr0;
                *(uint4*)&Vlds[nxt][(r0 + 32) * 72 + cc8] = vr1;
            }
        }

        // ---- l: lane sum done; butterfly over quads; redistribute to rows ----
        lp += __shfl_xor(lp, 16, 64);
        lp += __shfl_xor(lp, 32, 64);      // now lp = l[q=l16], uniform in quad
        float linv[4];
#pragma unroll
        for (int i = 0; i < 4; ++i)
            linv[i] = 1.0f / __shfl(lp, quad * 4 + i, 64);  // l for q=quad*4+i

        // ---- O write: lane owns rows quad*4+i, cols ni*16+l16 ----
        u16* ob = attn_out + (size_t)(b * SS + q0 + w * 16) * 1024 + h * 64;
#pragma unroll
        for (int ni = 0; ni < 4; ++ni)
#pragma unroll
            for (int i = 0; i < 4; ++i)
                ob[(size_t)(quad * 4 + i) * 1024 + ni * 16 + l16] =
                    f2bf(oacc[ni][i] * linv[i]);
    }
}

// ---------------------------------------------------------------------------
// Memory plan (ws = 32 MB proven + d_out as scratch):
//   d_out [0,8M)   hid_bf [4096][1024]   (dead once GEMM1 done; GEMM2
//                                          overwrites all 16MB at the end)
//   ws [0,6M)      w_in_bf               (dead after GEMM1)
//   ws [6M,+6KB)   b_in_bf               (dead after GEMM1)
//   ws [0,8M)      attn_ws (alias)       (written by attn, read by GEMM2)
//   ws [8M,16M)    Q  [4096][1024] bf16, pre-scaled  (dead after attn)
//   ws [8M,10M)    w_out_bf (alias, written after attn)
//   ws [10M,+2KB)  b_out_bf (alias)
//   ws [16M,24M)   K  [4096][1024] bf16
//   ws [24M,32M)   Vt [2][16][64][2048] bf16
// ---------------------------------------------------------------------------
extern "C" void kernel_launch(void* const* d_in, const int* in_sizes, int n_in,
                              void* d_out, int out_size, void* d_ws, size_t ws_size,
                              hipStream_t stream) {
    const float* hidden = (const float*)d_in[0];
    const float* w_in   = (const float*)d_in[1];
    const float* b_in   = (const float*)d_in[2];
    const float* w_out  = (const float*)d_in[3];
    const float* b_out  = (const float*)d_in[4];
    float* out = (float*)d_out;

    char* ws = (char*)d_ws;
    u16* hid_bf  = (u16*)d_out;                       // scratch in d_out
    u16* wi_bf   = (u16*)ws;
    u16* bi_bf   = (u16*)(ws + 6291456);
    u16* attn_ws = (u16*)ws;
    u16* Qbuf    = (u16*)(ws + 8388608);
    u16* wo_bf   = (u16*)(ws + 8388608);
    u16* bo_bf   = (u16*)(ws + 8388608 + 2097152);
    u16* Kbuf    = (u16*)(ws + 16777216);
    u16* Vtbuf   = (u16*)(ws + 25165824);

    cvt3bf<<<dim3(2048), dim3(256), 0, stream>>>(
        (const float4*)hidden, (uint2*)hid_bf, 1048576,
        (const float4*)w_in,   (uint2*)wi_bf,  786432,
        (const float4*)b_in,   (uint2*)bi_bf,  768);
    gemm_k2<128, 2><<<dim3(32, 24), dim3(256), 0, stream>>>(
        hid_bf, wi_bf, bi_bf, nullptr, Qbuf, Kbuf, Vtbuf, MM, H3, HH);
    attn_v4<<<dim3(16, NH, BB), dim3(256), 0, stream>>>(
        Qbuf, Kbuf, Vtbuf, attn_ws);
    cvt3bf<<<dim3(512), dim3(256), 0, stream>>>(
        (const float4*)w_out, (uint2*)wo_bf, 262144,
        (const float4*)b_out, (uint2*)bo_bf, 256,
        nullptr, nullptr, 0);
    gemm_k2<64, 1><<<dim3(32, 16), dim3(256), 0, stream>>>(
        attn_ws, wo_bf, bo_bf, out, nullptr, nullptr, nullptr, MM, HH, HH);
}

// Round 2
// 177.214 us; speedup vs baseline: 1.0528x; 1.0094x over previous
//
#include <hip/hip_runtime.h>
#include <hip/hip_bf16.h>

// Problem constants
#define BB 2
#define SS 2048
#define HH 1024
#define NH 16
#define DD 64
#define H3 3072
#define MM (BB*SS)   // 4096 rows

typedef unsigned short u16;
typedef unsigned int u32;
typedef __attribute__((ext_vector_type(8))) short bf16x8;
typedef __attribute__((ext_vector_type(4))) float f32x4;

__device__ __forceinline__ u16 f2bf(float f) {
    union { float f; u32 u; } v; v.f = f;
    u32 u = v.u;
    u += 0x7fffu + ((u >> 16) & 1u);   // RNE
    return (u16)(u >> 16);
}
__device__ __forceinline__ float bf2f(u16 h) {
    union { u32 u; float f; } v; v.u = ((u32)h) << 16;
    return v.f;
}
__device__ __forceinline__ u32 pack2bf(float a, float b) {
    __hip_bfloat162 h = __float22bfloat162_rn(float2{a, b});
    u32 u; __builtin_memcpy(&u, &h, 4);
    return u;
}
// async global->LDS, 16B/lane; LDS dest = wave-uniform base + lane*16B.
__device__ __forceinline__ void gl_lds16(const void* g, void* l) {
    __builtin_amdgcn_global_load_lds(
        (const __attribute__((address_space(1))) u32*)g,
        (__attribute__((address_space(3))) u32*)l, 16, 0, 0);
}
// inverse of the K row bit-permutation Rp (g -> R): R4=g2 R3=g4 R2=g3, rest id.
// ginv(R): g = (R5,R3,R2,R4,R1,R0).  Verified: ginv(Rp(g)) == g.
__device__ __forceinline__ int ginv(int R) {
    return (R & 35) | ((R & 8) << 1) | ((R & 4) << 1) | ((R & 16) >> 2);
}

// ---------------------------------------------------------------------------
// fp32 -> bf16 bulk convert, three buffers per launch
// ---------------------------------------------------------------------------
__global__ void cvt3bf(const float4* __restrict__ s0, uint2* __restrict__ d0, int n0,
                       const float4* __restrict__ s1, uint2* __restrict__ d1, int n1,
                       const float4* __restrict__ s2, uint2* __restrict__ d2, int n2) {
    int i = blockIdx.x * blockDim.x + threadIdx.x;
    const int tot = n0 + n1 + n2;
    for (; i < tot; i += gridDim.x * blockDim.x) {
        const float4* s; uint2* d; int j;
        if (i < n0)            { s = s0; d = d0; j = i; }
        else if (i < n0 + n1)  { s = s1; d = d1; j = i - n0; }
        else                   { s = s2; d = d2; j = i - n0 - n1; }
        float4 v = s[j];
        uint2 o; o.x = pack2bf(v.x, v.y); o.y = pack2bf(v.z, v.w);
        d[j] = o;
    }
}

// ---------------------------------------------------------------------------
// GEMM: C[M,N] = A[M,K] @ B[N,K]^T + bias.  BM=128, BK=32, BN template.
// A, B bf16, both staged via global_load_lds width-16 (m97 structure).
// MODE 1: fp32 out.  MODE 2: QKV epilogue -> Q (scaled 1/8), K, Vt (V^T).
// ---------------------------------------------------------------------------
template<int BN, int MODE>
__global__ __launch_bounds__(256, 2)
void gemm_k2(const u16* __restrict__ A, const u16* __restrict__ Bbf,
             const u16* __restrict__ biasbf, void* __restrict__ Cptr,
             u16* __restrict__ Qo, u16* __restrict__ Ko, u16* __restrict__ Vto,
             int M, int Nn, int K)
{
    constexpr int NFR = BN / 32;
    __shared__ __align__(16) u16 Alds[128 * 32];
    __shared__ __align__(16) u16 Blds[BN * 32];
    const int tid = threadIdx.x;
    const int w = tid >> 6, lane = tid & 63, quad = lane >> 4, l16 = lane & 15;
    const int m0 = blockIdx.x * 128, n0 = blockIdx.y * BN;
    const int wm = w >> 1, wn = w & 1;
    const int rA4 = lane >> 2, c8b = (lane & 3) * 8;   // gl_lds16: 4 lanes/row

    f32x4 acc[4][NFR] = {};

    for (int k0 = 0; k0 < K; k0 += 32) {
        __syncthreads();
        // A: wave w stages rows [w*32, w*32+32): 2 calls x 16 rows
#pragma unroll
        for (int q = 0; q < 2; ++q) {
            int row0 = w * 32 + q * 16;
            gl_lds16(&A[(size_t)(m0 + row0 + rA4) * K + k0 + c8b], &Alds[row0 * 32]);
        }
        // B: wave w stages rows [w*(BN/4), ...): BN/64 calls x 16 rows
#pragma unroll
        for (int q = 0; q < BN / 64; ++q) {
            int row0 = w * (BN / 4) + q * 16;
            gl_lds16(&Bbf[(size_t)(n0 + row0 + rA4) * K + k0 + c8b], &Blds[row0 * 32]);
        }
        __syncthreads();

        bf16x8 af[4], bfr[NFR];
#pragma unroll
        for (int mi = 0; mi < 4; ++mi)
            af[mi] = *(const bf16x8*)&Alds[(wm * 64 + mi * 16 + l16) * 32 + quad * 8];
#pragma unroll
        for (int ni = 0; ni < NFR; ++ni)
            bfr[ni] = *(const bf16x8*)&Blds[(wn * (BN / 2) + ni * 16 + l16) * 32 + quad * 8];
#pragma unroll
        for (int mi = 0; mi < 4; ++mi)
#pragma unroll
            for (int ni = 0; ni < NFR; ++ni)
                acc[mi][ni] = __builtin_amdgcn_mfma_f32_16x16x32_bf16(
                    af[mi], bfr[ni], acc[mi][ni], 0, 0, 0);
    }

    // epilogue: within 16x16 tile, row = quad*4+i, col = l16 (m89-verified)
#pragma unroll
    for (int mi = 0; mi < 4; ++mi) {
        int row_b = m0 + wm * 64 + mi * 16 + quad * 4;
#pragma unroll
        for (int ni = 0; ni < NFR; ++ni) {
            int col = n0 + wn * (BN / 2) + ni * 16 + l16;
            float bv = bf2f(biasbf[col]);
            if constexpr (MODE == 1) {
#pragma unroll
                for (int i = 0; i < 4; ++i)
                    ((float*)Cptr)[(size_t)(row_b + i) * Nn + col] = acc[mi][ni][i] + bv;
            } else {
                if (col < 1024) {            // Q, pre-scaled by 1/sqrt(D)
#pragma unroll
                    for (int i = 0; i < 4; ++i)
                        Qo[(size_t)(row_b + i) * 1024 + col] =
                            f2bf((acc[mi][ni][i] + bv) * 0.125f);
                } else if (col < 2048) {     // K
#pragma unroll
                    for (int i = 0; i < 4; ++i)
                        Ko[(size_t)(row_b + i) * 1024 + (col - 1024)] =
                            f2bf(acc[mi][ni][i] + bv);
                } else {                     // V -> Vt [b][h][d][s], pack 4 s
                    int d = col - 2048, hh = d >> 6, dd = d & 63;
                    int b = row_b >> 11, s = row_b & 2047;
                    u16 t0 = f2bf(acc[mi][ni][0] + bv), t1 = f2bf(acc[mi][ni][1] + bv);
                    u16 t2 = f2bf(acc[mi][ni][2] + bv), t3 = f2bf(acc[mi][ni][3] + bv);
                    uint2 pk; pk.x = (u32)t0 | ((u32)t1 << 16);
                    pk.y = (u32)t2 | ((u32)t3 << 16);
                    *(uint2*)&Vto[((size_t)((b * 16 + hh) * 64 + dd)) * 2048 + s] = pk;
                }
            }
        }
    }
}

// ---------------------------------------------------------------------------
// Causal flash attention v5.
// v4 (swapped QK^T, identity P repack via K row-permutation pi) +:
//  * K/V staging via global_load_lds DMA: zero ds_writes, zero staging VGPRs.
//    LDS is unpadded [64][64] u16; pi (ginv) and a T2 XOR chunk-swizzle
//    (chunk ^= row&7, 16B chunks) are folded into the per-lane GLOBAL source
//    address (G21: linear DMA dest + inverse-swizzled source + swizzled read).
//    Read bank-group = quad ^ (l16&7): 8 lanes / 4-bank group = conflict-free.
//  * XCD swizzle: flat 512-block grid decoded so all 16 q-blocks of one
//    (h,b) share bid%8 -> same XCD L2 holds that head's K/V (512KB of 4MB).
// ---------------------------------------------------------------------------
__global__ __launch_bounds__(256, 2)
void attn_v5(const u16* __restrict__ Q, const u16* __restrict__ Kb,
             const u16* __restrict__ Vt, u16* __restrict__ attn_out) {
    // bid = (g&7) + 8*((g>>3) + 4*pr), g = h + 16*b  (bijective on [0,512))
    const int bid = blockIdx.x;
    const int r8 = bid & 7, qq = bid >> 3;
    const int pr = qq >> 2, g = (qq & 3) * 8 + r8;
    const int h = g & 15, b = g >> 4;
    const int tid = threadIdx.x;
    const int w = tid >> 6, lane = tid & 63, quad = lane >> 4, l16 = lane & 15;
    __shared__ __align__(16) u16 Klds[2][64 * 64];
    __shared__ __align__(16) u16 Vlds[2][64 * 64];

    // staging geometry: wave w DMAs stripes {2w, 2w+1} of K and V.
    // stripe s = 1KB = rows s*8..s*8+7; lane covers (row s*8+sl, chunk cch).
    const int sl = lane >> 3, cch = lane & 7;
    const int rho0 = (2 * w) * 8 + sl, rho1 = (2 * w + 1) * 8 + sl;
    const int gcs = (cch ^ sl) * 8;          // XOR swizzle (row&7 == sl)
    const int kg0 = ginv(rho0), kg1 = ginv(rho1);   // K global row (pi^-1)
    const int ls0 = (2 * w) * 512, ls1 = (2 * w + 1) * 512;
    // read-side swizzled chunk offsets (u16 units)
    const int xk0 = (quad ^ (l16 & 7)) * 8;
    const int xk1 = ((quad + 4) ^ (l16 & 7)) * 8;

    for (int half = 0; half < 2; ++half) {
        const int qt = half ? pr : (31 - pr);        // uniform 33 iters/block
        const int q0 = qt * 64;
        const int T = qt + 1;

        const u16* Qb = Q  + (size_t)(b * SS + q0) * 1024 + h * 64;
        const u16* Kg = Kb + (size_t)(b * SS) * 1024 + h * 64;
        const u16* Vg = Vt + (size_t)((b * 16 + h) * 64) * 2048;

#define STAGE_T(kv0_, bi_) do {                                               \
        gl_lds16(&Kg[(size_t)((kv0_) + kg0) * 1024 + gcs], &Klds[bi_][ls0]);  \
        gl_lds16(&Kg[(size_t)((kv0_) + kg1) * 1024 + gcs], &Klds[bi_][ls1]);  \
        gl_lds16(&Vg[(size_t)rho0 * 2048 + (kv0_) + gcs], &Vlds[bi_][ls0]);   \
        gl_lds16(&Vg[(size_t)rho1 * 2048 + (kv0_) + gcs], &Vlds[bi_][ls1]);   \
    } while (0)

        bf16x8 qf0 = *(const bf16x8*)&Qb[(size_t)(w * 16 + l16) * 1024 + quad * 8];
        bf16x8 qf1 = *(const bf16x8*)&Qb[(size_t)(w * 16 + l16) * 1024 + 32 + quad * 8];

        f32x4 oacc[4] = {};
        float lp = 0.f;

        __syncthreads();          // prior half's reads of buf0 done
        STAGE_T(0, 0);

        for (int t = 0; t < T; ++t) {
            const int cur = t & 1;
            __syncthreads();   // vmcnt drained: tile t staged; buf cur^1 reads done
            if (t + 1 < T) STAGE_T((t + 1) * 64, cur ^ 1);
            const u16* Kc = Klds[cur];
            const u16* Vc = Vlds[cur];
            // ---- S^T = K Q^T : 64 kv (rows, pi-permuted) x 16 q (cols) ----
            f32x4 sacc[4] = {};
#pragma unroll
            for (int ni = 0; ni < 4; ++ni) {
                const int rb = (ni * 16 + l16) * 64;
                bf16x8 kf0 = *(const bf16x8*)&Kc[rb + xk0];
                bf16x8 kf1 = *(const bf16x8*)&Kc[rb + xk1];
                sacc[ni] = __builtin_amdgcn_mfma_f32_16x16x32_bf16(kf0, qf0, sacc[ni], 0, 0, 0);
                sacc[ni] = __builtin_amdgcn_mfma_f32_16x16x32_bf16(kf1, qf1, sacc[ni], 0, 0, 0);
            }
            // ---- P = exp(S): in-register, packed; mask only diagonal tile ----
            u32 pk[4][2];
            if (t + 1 < T) {                 // interior: kv < q0 <= q, no mask
#pragma unroll
                for (int ni = 0; ni < 4; ++ni) {
                    float p0 = __expf(sacc[ni][0]), p1 = __expf(sacc[ni][1]);
                    float p2 = __expf(sacc[ni][2]), p3 = __expf(sacc[ni][3]);
                    lp += (p0 + p1) + (p2 + p3);
                    pk[ni][0] = pack2bf(p0, p1);
                    pk[ni][1] = pack2bf(p2, p3);
                }
            } else {                         // diagonal: keep kv-pos <= w*16+l16
                const int thr = w * 16 + l16;
#pragma unroll
                for (int ni = 0; ni < 4; ++ni) {
                    const int pb = 32 * (ni >> 1) + 8 * quad + 4 * (ni & 1);
                    float pv[4];
#pragma unroll
                    for (int i = 0; i < 4; ++i) {
                        float e = __expf(sacc[ni][i]);
                        pv[i] = (pb + i <= thr) ? e : 0.f;
                    }
                    lp += (pv[0] + pv[1]) + (pv[2] + pv[3]);
                    pk[ni][0] = pack2bf(pv[0], pv[1]);
                    pk[ni][1] = pack2bf(pv[2], pv[3]);
                }
            }
            // P A-fragment = identity repack (thanks to K row permutation)
            union { u32 u[4]; bf16x8 v; } pf0, pf1;
            pf0.u[0] = pk[0][0]; pf0.u[1] = pk[0][1];
            pf0.u[2] = pk[1][0]; pf0.u[3] = pk[1][1];
            pf1.u[0] = pk[2][0]; pf1.u[1] = pk[2][1];
            pf1.u[2] = pk[3][0]; pf1.u[3] = pk[3][1];
            // ---- O += P V ----
#pragma unroll
            for (int ni = 0; ni < 4; ++ni) {
                const int rb = (ni * 16 + l16) * 64;
                bf16x8 vf0 = *(const bf16x8*)&Vc[rb + xk0];
                bf16x8 vf1 = *(const bf16x8*)&Vc[rb + xk1];
                oacc[ni] = __builtin_amdgcn_mfma_f32_16x16x32_bf16(pf0.v, vf0, oacc[ni], 0, 0, 0);
                oacc[ni] = __builtin_amdgcn_mfma_f32_16x16x32_bf16(pf1.v, vf1, oacc[ni], 0, 0, 0);
            }
        }

        // ---- l: lane sum done; butterfly over quads; redistribute to rows ----
        lp += __shfl_xor(lp, 16, 64);
        lp += __shfl_xor(lp, 32, 64);      // now lp = l[q=l16], uniform in quad
        float linv[4];
#pragma unroll
        for (int i = 0; i < 4; ++i)
            linv[i] = 1.0f / __shfl(lp, quad * 4 + i, 64);  // l for q=quad*4+i

        // ---- O write: lane owns rows quad*4+i, cols ni*16+l16 ----
        u16* ob = attn_out + (size_t)(b * SS + q0 + w * 16) * 1024 + h * 64;
#pragma unroll
        for (int ni = 0; ni < 4; ++ni)
#pragma unroll
            for (int i = 0; i < 4; ++i)
                ob[(size_t)(quad * 4 + i) * 1024 + ni * 16 + l16] =
                    f2bf(oacc[ni][i] * linv[i]);
#undef STAGE_T
    }
}

// ---------------------------------------------------------------------------
// Memory plan (ws = 32 MB proven + d_out as scratch):
//   d_out [0,8M)   hid_bf [4096][1024]   (dead once GEMM1 done; GEMM2
//                                          overwrites all 16MB at the end)
//   ws [0,6M)      w_in_bf               (dead after GEMM1)
//   ws [6M,+6KB)   b_in_bf               (dead after GEMM1)
//   ws [0,8M)      attn_ws (alias)       (written by attn, read by GEMM2)
//   ws [8M,16M)    Q  [4096][1024] bf16, pre-scaled  (dead after attn)
//   ws [8M,10M)    w_out_bf (alias, written after attn)
//   ws [10M,+2KB)  b_out_bf (alias)
//   ws [16M,24M)   K  [4096][1024] bf16
//   ws [24M,32M)   Vt [2][16][64][2048] bf16
// ---------------------------------------------------------------------------
extern "C" void kernel_launch(void* const* d_in, const int* in_sizes, int n_in,
                              void* d_out, int out_size, void* d_ws, size_t ws_size,
                              hipStream_t stream) {
    const float* hidden = (const float*)d_in[0];
    const float* w_in   = (const float*)d_in[1];
    const float* b_in   = (const float*)d_in[2];
    const float* w_out  = (const float*)d_in[3];
    const float* b_out  = (const float*)d_in[4];
    float* out = (float*)d_out;

    char* ws = (char*)d_ws;
    u16* hid_bf  = (u16*)d_out;                       // scratch in d_out
    u16* wi_bf   = (u16*)ws;
    u16* bi_bf   = (u16*)(ws + 6291456);
    u16* attn_ws = (u16*)ws;
    u16* Qbuf    = (u16*)(ws + 8388608);
    u16* wo_bf   = (u16*)(ws + 8388608);
    u16* bo_bf   = (u16*)(ws + 8388608 + 2097152);
    u16* Kbuf    = (u16*)(ws + 16777216);
    u16* Vtbuf   = (u16*)(ws + 25165824);

    cvt3bf<<<dim3(2048), dim3(256), 0, stream>>>(
        (const float4*)hidden, (uint2*)hid_bf, 1048576,
        (const float4*)w_in,   (uint2*)wi_bf,  786432,
        (const float4*)b_in,   (uint2*)bi_bf,  768);
    gemm_k2<128, 2><<<dim3(32, 24), dim3(256), 0, stream>>>(
        hid_bf, wi_bf, bi_bf, nullptr, Qbuf, Kbuf, Vtbuf, MM, H3, HH);
    attn_v5<<<dim3(512), dim3(256), 0, stream>>>(
        Qbuf, Kbuf, Vtbuf, attn_ws);
    cvt3bf<<<dim3(512), dim3(256), 0, stream>>>(
        (const float4*)w_out, (uint2*)wo_bf, 262144,
        (const float4*)b_out, (uint2*)bo_bf, 256,
        nullptr, nullptr, 0);
    gemm_k2<64, 1><<<dim3(32, 16), dim3(256), 0, stream>>>(
        attn_ws, wo_bf, bo_bf, out, nullptr, nullptr, nullptr, MM, HH, HH);
}

// Round 3
// 173.911 us; speedup vs baseline: 1.0728x; 1.0190x over previous
//
#include <hip/hip_runtime.h>
#include <hip/hip_bf16.h>

// Problem constants
#define BB 2
#define SS 2048
#define HH 1024
#define NH 16
#define DD 64
#define H3 3072
#define MM (BB*SS)   // 4096 rows

typedef unsigned short u16;
typedef unsigned int u32;
typedef __attribute__((ext_vector_type(8))) short bf16x8;
typedef __attribute__((ext_vector_type(4))) float f32x4;

__device__ __forceinline__ u16 f2bf(float f) {
    union { float f; u32 u; } v; v.f = f;
    u32 u = v.u;
    u += 0x7fffu + ((u >> 16) & 1u);   // RNE
    return (u16)(u >> 16);
}
__device__ __forceinline__ float bf2f(u16 h) {
    union { u32 u; float f; } v; v.u = ((u32)h) << 16;
    return v.f;
}
__device__ __forceinline__ u32 pack2bf(float a, float b) {
    __hip_bfloat162 h = __float22bfloat162_rn(float2{a, b});
    u32 u; __builtin_memcpy(&u, &h, 4);
    return u;
}
// async global->LDS, 16B/lane; LDS dest = wave-uniform base + lane*16B.
__device__ __forceinline__ void gl_lds16(const void* g, void* l) {
    __builtin_amdgcn_global_load_lds(
        (const __attribute__((address_space(1))) u32*)g,
        (__attribute__((address_space(3))) u32*)l, 16, 0, 0);
}
// inverse of the K row bit-permutation Rp (g -> R): R4=g2 R3=g4 R2=g3, rest id.
// ginv(R): g = (R5,R3,R2,R4,R1,R0).  Verified: ginv(Rp(g)) == g.
__device__ __forceinline__ int ginv(int R) {
    return (R & 35) | ((R & 8) << 1) | ((R & 4) << 1) | ((R & 16) >> 2);
}

// ---------------------------------------------------------------------------
// fp32 -> bf16 bulk convert, three buffers per launch
// ---------------------------------------------------------------------------
__global__ void cvt3bf(const float4* __restrict__ s0, uint2* __restrict__ d0, int n0,
                       const float4* __restrict__ s1, uint2* __restrict__ d1, int n1,
                       const float4* __restrict__ s2, uint2* __restrict__ d2, int n2) {
    int i = blockIdx.x * blockDim.x + threadIdx.x;
    const int tot = n0 + n1 + n2;
    for (; i < tot; i += gridDim.x * blockDim.x) {
        const float4* s; uint2* d; int j;
        if (i < n0)            { s = s0; d = d0; j = i; }
        else if (i < n0 + n1)  { s = s1; d = d1; j = i - n0; }
        else                   { s = s2; d = d2; j = i - n0 - n1; }
        float4 v = s[j];
        uint2 o; o.x = pack2bf(v.x, v.y); o.y = pack2bf(v.z, v.w);
        d[j] = o;
    }
}

// ---------------------------------------------------------------------------
// GEMM: C[M,N] = A[M,K] @ B[N,K]^T + bias.  BM=128, BK=32, BN template.
// T3-min 2-phase: LDS double-buffered, tile t+1 DMA'd (global_load_lds)
// during tile t's compute, ONE __syncthreads per K-step (its vmcnt(0) drain
// covers loads that had a full compute phase in flight).  3 blocks/CU:
// gemm1's 768-block grid fills 256 CUs in exactly one round (no tail).
// MODE 1: fp32 out.  MODE 2: QKV epilogue -> Q (scaled 1/8), K, Vt (V^T).
// ---------------------------------------------------------------------------
template<int BN, int MODE>
__global__ __launch_bounds__(256, 3)
void gemm_k2(const u16* __restrict__ A, const u16* __restrict__ Bbf,
             const u16* __restrict__ biasbf, void* __restrict__ Cptr,
             u16* __restrict__ Qo, u16* __restrict__ Ko, u16* __restrict__ Vto,
             int M, int Nn, int K)
{
    constexpr int NFR = BN / 32;
    __shared__ __align__(16) u16 Alds[2][128 * 32];
    __shared__ __align__(16) u16 Blds[2][BN * 32];
    const int tid = threadIdx.x;
    const int w = tid >> 6, lane = tid & 63, quad = lane >> 4, l16 = lane & 15;
    const int m0 = blockIdx.x * 128, n0 = blockIdx.y * BN;
    const int wm = w >> 1, wn = w & 1;
    const int rA4 = lane >> 2, c8b = (lane & 3) * 8;   // gl_lds16: 4 lanes/row

    f32x4 acc[4][NFR] = {};

#define GSTAGE(k0_, bi_) do {                                                  \
    _Pragma("unroll")                                                          \
    for (int q = 0; q < 2; ++q) {                                              \
        int row0 = w * 32 + q * 16;                                            \
        gl_lds16(&A[(size_t)(m0 + row0 + rA4) * K + (k0_) + c8b],              \
                 &Alds[bi_][row0 * 32]);                                       \
    }                                                                          \
    _Pragma("unroll")                                                          \
    for (int q = 0; q < BN / 64; ++q) {                                        \
        int row0 = w * (BN / 4) + q * 16;                                      \
        gl_lds16(&Bbf[(size_t)(n0 + row0 + rA4) * K + (k0_) + c8b],            \
                 &Blds[bi_][row0 * 32]);                                       \
    }                                                                          \
} while (0)

    const int NT = K >> 5;
    GSTAGE(0, 0);
    for (int t = 0; t < NT; ++t) {
        const int cur = t & 1;
        __syncthreads();   // vmcnt(0) drain: tile t visible; buf cur^1 reads done
        if (t + 1 < NT) GSTAGE((t + 1) << 5, cur ^ 1);

        bf16x8 af[4], bfr[NFR];
#pragma unroll
        for (int mi = 0; mi < 4; ++mi)
            af[mi] = *(const bf16x8*)&Alds[cur][(wm * 64 + mi * 16 + l16) * 32 + quad * 8];
#pragma unroll
        for (int ni = 0; ni < NFR; ++ni)
            bfr[ni] = *(const bf16x8*)&Blds[cur][(wn * (BN / 2) + ni * 16 + l16) * 32 + quad * 8];
#pragma unroll
        for (int mi = 0; mi < 4; ++mi)
#pragma unroll
            for (int ni = 0; ni < NFR; ++ni)
                acc[mi][ni] = __builtin_amdgcn_mfma_f32_16x16x32_bf16(
                    af[mi], bfr[ni], acc[mi][ni], 0, 0, 0);
    }
#undef GSTAGE

    // epilogue: within 16x16 tile, row = quad*4+i, col = l16 (m89-verified)
#pragma unroll
    for (int mi = 0; mi < 4; ++mi) {
        int row_b = m0 + wm * 64 + mi * 16 + quad * 4;
#pragma unroll
        for (int ni = 0; ni < NFR; ++ni) {
            int col = n0 + wn * (BN / 2) + ni * 16 + l16;
            float bv = bf2f(biasbf[col]);
            if constexpr (MODE == 1) {
#pragma unroll
                for (int i = 0; i < 4; ++i)
                    ((float*)Cptr)[(size_t)(row_b + i) * Nn + col] = acc[mi][ni][i] + bv;
            } else {
                if (col < 1024) {            // Q, pre-scaled by 1/sqrt(D)
#pragma unroll
                    for (int i = 0; i < 4; ++i)
                        Qo[(size_t)(row_b + i) * 1024 + col] =
                            f2bf((acc[mi][ni][i] + bv) * 0.125f);
                } else if (col < 2048) {     // K
#pragma unroll
                    for (int i = 0; i < 4; ++i)
                        Ko[(size_t)(row_b + i) * 1024 + (col - 1024)] =
                            f2bf(acc[mi][ni][i] + bv);
                } else {                     // V -> Vt [b][h][d][s], pack 4 s
                    int d = col - 2048, hh = d >> 6, dd = d & 63;
                    int b = row_b >> 11, s = row_b & 2047;
                    u16 t0 = f2bf(acc[mi][ni][0] + bv), t1 = f2bf(acc[mi][ni][1] + bv);
                    u16 t2 = f2bf(acc[mi][ni][2] + bv), t3 = f2bf(acc[mi][ni][3] + bv);
                    uint2 pk; pk.x = (u32)t0 | ((u32)t1 << 16);
                    pk.y = (u32)t2 | ((u32)t3 << 16);
                    *(uint2*)&Vto[((size_t)((b * 16 + hh) * 64 + dd)) * 2048 + s] = pk;
                }
            }
        }
    }
}

// ---------------------------------------------------------------------------
// Causal flash attention v5 (unchanged this round).
// Swapped QK^T, identity P repack via K row-permutation pi, K/V staged via
// global_load_lds DMA with pi + T2 XOR chunk-swizzle folded into the global
// source address (G21), conflict-free reads, XCD-swizzled grid.
// ---------------------------------------------------------------------------
__global__ __launch_bounds__(256, 2)
void attn_v5(const u16* __restrict__ Q, const u16* __restrict__ Kb,
             const u16* __restrict__ Vt, u16* __restrict__ attn_out) {
    // bid = (g&7) + 8*((g>>3) + 4*pr), g = h + 16*b  (bijective on [0,512))
    const int bid = blockIdx.x;
    const int r8 = bid & 7, qq = bid >> 3;
    const int pr = qq >> 2, g = (qq & 3) * 8 + r8;
    const int h = g & 15, b = g >> 4;
    const int tid = threadIdx.x;
    const int w = tid >> 6, lane = tid & 63, quad = lane >> 4, l16 = lane & 15;
    __shared__ __align__(16) u16 Klds[2][64 * 64];
    __shared__ __align__(16) u16 Vlds[2][64 * 64];

    // staging geometry: wave w DMAs stripes {2w, 2w+1} of K and V.
    // stripe s = 1KB = rows s*8..s*8+7; lane covers (row s*8+sl, chunk cch).
    const int sl = lane >> 3, cch = lane & 7;
    const int rho0 = (2 * w) * 8 + sl, rho1 = (2 * w + 1) * 8 + sl;
    const int gcs = (cch ^ sl) * 8;          // XOR swizzle (row&7 == sl)
    const int kg0 = ginv(rho0), kg1 = ginv(rho1);   // K global row (pi^-1)
    const int ls0 = (2 * w) * 512, ls1 = (2 * w + 1) * 512;
    // read-side swizzled chunk offsets (u16 units)
    const int xk0 = (quad ^ (l16 & 7)) * 8;
    const int xk1 = ((quad + 4) ^ (l16 & 7)) * 8;

    for (int half = 0; half < 2; ++half) {
        const int qt = half ? pr : (31 - pr);        // uniform 33 iters/block
        const int q0 = qt * 64;
        const int T = qt + 1;

        const u16* Qb = Q  + (size_t)(b * SS + q0) * 1024 + h * 64;
        const u16* Kg = Kb + (size_t)(b * SS) * 1024 + h * 64;
        const u16* Vg = Vt + (size_t)((b * 16 + h) * 64) * 2048;

#define STAGE_T(kv0_, bi_) do {                                               \
        gl_lds16(&Kg[(size_t)((kv0_) + kg0) * 1024 + gcs], &Klds[bi_][ls0]);  \
        gl_lds16(&Kg[(size_t)((kv0_) + kg1) * 1024 + gcs], &Klds[bi_][ls1]);  \
        gl_lds16(&Vg[(size_t)rho0 * 2048 + (kv0_) + gcs], &Vlds[bi_][ls0]);   \
        gl_lds16(&Vg[(size_t)rho1 * 2048 + (kv0_) + gcs], &Vlds[bi_][ls1]);   \
    } while (0)

        bf16x8 qf0 = *(const bf16x8*)&Qb[(size_t)(w * 16 + l16) * 1024 + quad * 8];
        bf16x8 qf1 = *(const bf16x8*)&Qb[(size_t)(w * 16 + l16) * 1024 + 32 + quad * 8];

        f32x4 oacc[4] = {};
        float lp = 0.f;

        __syncthreads();          // prior half's reads of buf0 done
        STAGE_T(0, 0);

        for (int t = 0; t < T; ++t) {
            const int cur = t & 1;
            __syncthreads();   // vmcnt drained: tile t staged; buf cur^1 reads done
            if (t + 1 < T) STAGE_T((t + 1) * 64, cur ^ 1);
            const u16* Kc = Klds[cur];
            const u16* Vc = Vlds[cur];
            // ---- S^T = K Q^T : 64 kv (rows, pi-permuted) x 16 q (cols) ----
            f32x4 sacc[4] = {};
#pragma unroll
            for (int ni = 0; ni < 4; ++ni) {
                const int rb = (ni * 16 + l16) * 64;
                bf16x8 kf0 = *(const bf16x8*)&Kc[rb + xk0];
                bf16x8 kf1 = *(const bf16x8*)&Kc[rb + xk1];
                sacc[ni] = __builtin_amdgcn_mfma_f32_16x16x32_bf16(kf0, qf0, sacc[ni], 0, 0, 0);
                sacc[ni] = __builtin_amdgcn_mfma_f32_16x16x32_bf16(kf1, qf1, sacc[ni], 0, 0, 0);
            }
            // ---- P = exp(S): in-register, packed; mask only diagonal tile ----
            u32 pk[4][2];
            if (t + 1 < T) {                 // interior: kv < q0 <= q, no mask
#pragma unroll
                for (int ni = 0; ni < 4; ++ni) {
                    float p0 = __expf(sacc[ni][0]), p1 = __expf(sacc[ni][1]);
                    float p2 = __expf(sacc[ni][2]), p3 = __expf(sacc[ni][3]);
                    lp += (p0 + p1) + (p2 + p3);
                    pk[ni][0] = pack2bf(p0, p1);
                    pk[ni][1] = pack2bf(p2, p3);
                }
            } else {                         // diagonal: keep kv-pos <= w*16+l16
                const int thr = w * 16 + l16;
#pragma unroll
                for (int ni = 0; ni < 4; ++ni) {
                    const int pb = 32 * (ni >> 1) + 8 * quad + 4 * (ni & 1);
                    float pv[4];
#pragma unroll
                    for (int i = 0; i < 4; ++i) {
                        float e = __expf(sacc[ni][i]);
                        pv[i] = (pb + i <= thr) ? e : 0.f;
                    }
                    lp += (pv[0] + pv[1]) + (pv[2] + pv[3]);
                    pk[ni][0] = pack2bf(pv[0], pv[1]);
                    pk[ni][1] = pack2bf(pv[2], pv[3]);
                }
            }
            // P A-fragment = identity repack (thanks to K row permutation)
            union { u32 u[4]; bf16x8 v; } pf0, pf1;
            pf0.u[0] = pk[0][0]; pf0.u[1] = pk[0][1];
            pf0.u[2] = pk[1][0]; pf0.u[3] = pk[1][1];
            pf1.u[0] = pk[2][0]; pf1.u[1] = pk[2][1];
            pf1.u[2] = pk[3][0]; pf1.u[3] = pk[3][1];
            // ---- O += P V ----
#pragma unroll
            for (int ni = 0; ni < 4; ++ni) {
                const int rb = (ni * 16 + l16) * 64;
                bf16x8 vf0 = *(const bf16x8*)&Vc[rb + xk0];
                bf16x8 vf1 = *(const bf16x8*)&Vc[rb + xk1];
                oacc[ni] = __builtin_amdgcn_mfma_f32_16x16x32_bf16(pf0.v, vf0, oacc[ni], 0, 0, 0);
                oacc[ni] = __builtin_amdgcn_mfma_f32_16x16x32_bf16(pf1.v, vf1, oacc[ni], 0, 0, 0);
            }
        }

        // ---- l: lane sum done; butterfly over quads; redistribute to rows ----
        lp += __shfl_xor(lp, 16, 64);
        lp += __shfl_xor(lp, 32, 64);      // now lp = l[q=l16], uniform in quad
        float linv[4];
#pragma unroll
        for (int i = 0; i < 4; ++i)
            linv[i] = 1.0f / __shfl(lp, quad * 4 + i, 64);  // l for q=quad*4+i

        // ---- O write: lane owns rows quad*4+i, cols ni*16+l16 ----
        u16* ob = attn_out + (size_t)(b * SS + q0 + w * 16) * 1024 + h * 64;
#pragma unroll
        for (int ni = 0; ni < 4; ++ni)
#pragma unroll
            for (int i = 0; i < 4; ++i)
                ob[(size_t)(quad * 4 + i) * 1024 + ni * 16 + l16] =
                    f2bf(oacc[ni][i] * linv[i]);
#undef STAGE_T
    }
}

// ---------------------------------------------------------------------------
// Memory plan (ws = 32 MB proven + d_out as scratch):
//   d_out [0,8M)   hid_bf [4096][1024]   (dead once GEMM1 done; GEMM2
//                                          overwrites all 16MB at the end)
//   ws [0,6M)      w_in_bf               (dead after GEMM1)
//   ws [6M,+6KB)   b_in_bf               (dead after GEMM1)
//   ws [0,8M)      attn_ws (alias)       (written by attn, read by GEMM2)
//   ws [8M,16M)    Q  [4096][1024] bf16, pre-scaled  (dead after attn)
//   ws [8M,10M)    w_out_bf (alias, written after attn)
//   ws [10M,+2KB)  b_out_bf (alias)
//   ws [16M,24M)   K  [4096][1024] bf16
//   ws [24M,32M)   Vt [2][16][64][2048] bf16
// ---------------------------------------------------------------------------
extern "C" void kernel_launch(void* const* d_in, const int* in_sizes, int n_in,
                              void* d_out, int out_size, void* d_ws, size_t ws_size,
                              hipStream_t stream) {
    const float* hidden = (const float*)d_in[0];
    const float* w_in   = (const float*)d_in[1];
    const float* b_in   = (const float*)d_in[2];
    const float* w_out  = (const float*)d_in[3];
    const float* b_out  = (const float*)d_in[4];
    float* out = (float*)d_out;

    char* ws = (char*)d_ws;
    u16* hid_bf  = (u16*)d_out;                       // scratch in d_out
    u16* wi_bf   = (u16*)ws;
    u16* bi_bf   = (u16*)(ws + 6291456);
    u16* attn_ws = (u16*)ws;
    u16* Qbuf    = (u16*)(ws + 8388608);
    u16* wo_bf   = (u16*)(ws + 8388608);
    u16* bo_bf   = (u16*)(ws + 8388608 + 2097152);
    u16* Kbuf    = (u16*)(ws + 16777216);
    u16* Vtbuf   = (u16*)(ws + 25165824);

    cvt3bf<<<dim3(2048), dim3(256), 0, stream>>>(
        (const float4*)hidden, (uint2*)hid_bf, 1048576,
        (const float4*)w_in,   (uint2*)wi_bf,  786432,
        (const float4*)b_in,   (uint2*)bi_bf,  768);
    gemm_k2<128, 2><<<dim3(32, 24), dim3(256), 0, stream>>>(
        hid_bf, wi_bf, bi_bf, nullptr, Qbuf, Kbuf, Vtbuf, MM, H3, HH);
    attn_v5<<<dim3(512), dim3(256), 0, stream>>>(
        Qbuf, Kbuf, Vtbuf, attn_ws);
    cvt3bf<<<dim3(512), dim3(256), 0, stream>>>(
        (const float4*)w_out, (uint2*)wo_bf, 262144,
        (const float4*)b_out, (uint2*)bo_bf, 256,
        nullptr, nullptr, 0);
    gemm_k2<64, 1><<<dim3(32, 16), dim3(256), 0, stream>>>(
        attn_ws, wo_bf, bo_bf, out, nullptr, nullptr, nullptr, MM, HH, HH);
}